// Round 9
// baseline (16.546 us; speedup 1.0000x reference)
//
#include <hip/hip_runtime.h>
#include <math.h>

// Closed form (derived R2, verified vs full statevector sim in R1):
//   e0 = e2 = e3 = 0;  e1 = -cos^2(1) * cos(pi/2 * w1),  w1 = in[:,4].
//
// R9 = exact revert to R7 (best measured: 9.82us).
//   - 1 row/thread, max TLP (R6 proved TLP > ILP for this stream)
//   - cached loads (R8 showed NT load costs ~0.4us: L2 line retention across
//     waves at 20B stride is real reuse)
//   - nontemporal float4 stores (R7 showed -0.6us: write-once stream)
typedef float floatx4 __attribute__((ext_vector_type(4)));

__global__ __launch_bounds__(256) void qlayer_kernel(
    const float* __restrict__ in, floatx4* __restrict__ out4, int B)
{
    int b = blockIdx.x * blockDim.x + threadIdx.x;
    if (b >= B) return;

    const float w1 = in[5 * b + 4];
    const float c = __cosf(1.5707963267948966f * w1);      // w1 in [0,1)
    const float e1 = -0.2919265817264289f * c;             // -cos^2(1) * c

    floatx4 o = {0.0f, e1, 0.0f, 0.0f};
    __builtin_nontemporal_store(o, &out4[b]);
}

extern "C" void kernel_launch(void* const* d_in, const int* in_sizes, int n_in,
                              void* d_out, int out_size, void* d_ws, size_t ws_size,
                              hipStream_t stream) {
    const float* in = (const float*)d_in[0];
    floatx4* out4 = (floatx4*)d_out;
    const int B = in_sizes[0] / 5;  // (B,5) float32
    const int block = 256;
    const int grid = (B + block - 1) / block;
    qlayer_kernel<<<grid, block, 0, stream>>>(in, out4, B);
}